// Round 2
// baseline (620.096 us; speedup 1.0000x reference)
//
#include <hip/hip_runtime.h>
#include <math.h>

typedef _Float16 f16;
typedef _Float16 f16x4 __attribute__((ext_vector_type(4)));
typedef _Float16 f16x8 __attribute__((ext_vector_type(8)));
typedef float f32x4 __attribute__((ext_vector_type(4)));

#define T_TOK 2048
#define DDIM  1024
#define FDIM  512
#define NEXP  64
#define TOPK  8
#define NPAIR (T_TOK * TOPK)
#define MAXTILES 192   // sum ceil(cnt_e/128) <= 16384/128 + 64 = 192

// ---------------- workspace layout (bytes) ----------------
static constexpr size_t OFF_XH    = 0;                                      // fp16 [T][D]   4 MiB
static constexpr size_t OFF_WSUPT = OFF_XH    + (size_t)T_TOK * DDIM * 2;   // fp16 [F][D]   1 MiB
static constexpr size_t OFF_WSDNT = OFF_WSUPT + (size_t)FDIM * DDIM * 2;    // fp16 [D][F]   1 MiB
static constexpr size_t OFF_WUPT  = OFF_WSDNT + (size_t)DDIM * FDIM * 2;    // fp16 [E][F][D] 64 MiB
static constexpr size_t OFF_WDNT  = OFF_WUPT  + (size_t)NEXP * FDIM * DDIM * 2; // fp16 [E][D][F] 64 MiB
static constexpr size_t OFF_SHH   = OFF_WDNT  + (size_t)NEXP * DDIM * FDIM * 2; // fp16 [T][F]   2 MiB
static constexpr size_t OFF_HP    = OFF_SHH   + (size_t)T_TOK * FDIM * 2;   // fp16 [NPAIR][F] 16 MiB
static constexpr size_t OFF_IDX   = OFF_HP    + (size_t)NPAIR * FDIM * 2;   // int  [T][8]
static constexpr size_t OFF_WB    = OFF_IDX   + (size_t)NPAIR * 4;          // float [T][8]
static constexpr size_t OFF_CNT   = OFF_WB    + (size_t)NPAIR * 4;          // int[64]
static constexpr size_t OFF_OFFS  = OFF_CNT   + 256;                        // int[65]
static constexpr size_t OFF_FILL  = OFF_OFFS  + 512;                        // int[64]
static constexpr size_t OFF_NT    = OFF_FILL  + 256;                        // int[1]
static constexpr size_t OFF_TOK   = OFF_NT    + 256;                        // int[NPAIR]
static constexpr size_t OFF_PW    = OFF_TOK   + (size_t)NPAIR * 4;          // float[NPAIR]
static constexpr size_t OFF_DESC  = OFF_PW    + (size_t)NPAIR * 4;          // int4[256]

__device__ __forceinline__ void async_ld16(void* lds, const void* g) {
  __builtin_amdgcn_global_load_lds(
      (const __attribute__((address_space(1))) void*)g,
      (__attribute__((address_space(3))) void*)lds, 16, 0, 0);
}

// ---------------- small kernels ----------------
__global__ void zero_cnt_kernel(int* cnt) {
  if (threadIdx.x < NEXP) cnt[threadIdx.x] = 0;
}

// src fp32 [R][C] -> dst fp16 [C][R]; R,C multiples of 64; slab = blockIdx.z
__global__ __launch_bounds__(256)
void transpose_f32_f16_kernel(const float* __restrict__ src0,
                              f16* __restrict__ dst0, int R, int C) {
  __shared__ float tile[64][65];
  const float* src = src0 + (size_t)blockIdx.z * R * C;
  f16* dst = dst0 + (size_t)blockIdx.z * R * C;
  int r0 = blockIdx.y * 64, c0 = blockIdx.x * 64;
  int t = threadIdx.x;
#pragma unroll
  for (int p = 0; p < 4; ++p) {
    int q = t + p * 256;
    int r = q >> 4, c4 = (q & 15) * 4;
    float4 v = *(const float4*)(src + (size_t)(r0 + r) * C + c0 + c4);
    tile[r][c4 + 0] = v.x; tile[r][c4 + 1] = v.y;
    tile[r][c4 + 2] = v.z; tile[r][c4 + 3] = v.w;
  }
  __syncthreads();
#pragma unroll
  for (int p = 0; p < 4; ++p) {
    int q = t + p * 256;
    int rr = q >> 4, cc4 = (q & 15) * 4;
    f16x4 h = { (f16)tile[cc4 + 0][rr], (f16)tile[cc4 + 1][rr],
                (f16)tile[cc4 + 2][rr], (f16)tile[cc4 + 3][rr] };
    *(f16x4*)(dst + (size_t)(c0 + rr) * R + r0 + cc4) = h;
  }
}

// ---------------- routing (exact fp32) + fused x->fp16 ----------------
// 4 tokens per block; wave w handles token t0+w; lane = expert.
__global__ __launch_bounds__(256)
void routing_kernel(const float* __restrict__ x, const float* __restrict__ cent,
                    const float* __restrict__ bias, int* __restrict__ idxbuf,
                    float* __restrict__ wbuf, int* __restrict__ cnt,
                    f16* __restrict__ xh) {
  __shared__ float xs[4][DDIM];
  int t0 = blockIdx.x * 4;
  int tid = threadIdx.x;
#pragma unroll
  for (int p = 0; p < 4; ++p) {
    int q = tid + p * 256;           // 0..1023
    int sub = q >> 8, d4 = (q & 255) * 4;
    *(float4*)&xs[sub][d4] = *(const float4*)(x + (size_t)(t0 + sub) * DDIM + d4);
  }
  __syncthreads();
  // fused fp32->fp16 conversion of x (feeds all GEMM A-operands)
#pragma unroll
  for (int p = 0; p < 4; ++p) {
    int q = tid + p * 256;
    int sub = q >> 8, d4 = (q & 255) * 4;
    f16x4 h = { (f16)xs[sub][d4], (f16)xs[sub][d4 + 1],
                (f16)xs[sub][d4 + 2], (f16)xs[sub][d4 + 3] };
    *(f16x4*)(xh + (size_t)(t0 + sub) * DDIM + d4) = h;
  }
  int lane = tid & 63;
  int sub = tid >> 6;
  int token = t0 + sub;
  const float* c = cent + (size_t)lane * DDIM;
  float aff = 0.f;
  for (int d = 0; d < DDIM; d += 4) {
    float4 cv = *(const float4*)(c + d);
    aff += cv.x * xs[sub][d] + cv.y * xs[sub][d + 1] +
           cv.z * xs[sub][d + 2] + cv.w * xs[sub][d + 3];
  }
  float sc = aff + bias[lane];
  bool picked = false;
  int selidx = 0;
  for (int p = 0; p < TOPK; ++p) {
    float v = picked ? -3.0e38f : sc;
    int ix = lane;
#pragma unroll
    for (int off = 32; off; off >>= 1) {
      float ov = __shfl_xor(v, off);
      int oi = __shfl_xor(ix, off);
      if (ov > v || (ov == v && oi < ix)) { v = ov; ix = oi; }
    }
    if (lane == ix) picked = true;
    if (lane == p) selidx = ix;       // lane p records p-th winner
  }
  float rawa = __shfl(aff, selidx);   // unbiased score of selection (lanes 0..7)
  float s = 1.f / (1.f + expf(-rawa));
  float sum = s;
  sum += __shfl_xor(sum, 1); sum += __shfl_xor(sum, 2); sum += __shfl_xor(sum, 4);
  float wg = s / (sum + 1e-8f);
  if (lane < TOPK) {
    idxbuf[token * TOPK + lane] = selidx;
    wbuf[token * TOPK + lane] = wg;
    atomicAdd(&cnt[selidx], 1);
  }
}

// ---------------- scan + tile-descriptor build ----------------
__global__ void scan_desc_kernel(const int* __restrict__ cnt, int* __restrict__ offs,
                                 int* __restrict__ fill, int4* __restrict__ desc,
                                 int* __restrict__ ntiles) {
  if (threadIdx.x < NEXP) fill[threadIdx.x] = 0;
  if (threadIdx.x == 0) {
    int acc = 0, nt = 0;
    for (int e = 0; e < NEXP; ++e) {
      offs[e] = acc;
      int c = cnt[e];
      for (int r = 0; r < c; r += 128)
        desc[nt++] = make_int4(e, acc + r, min(128, c - r), 0);
      acc += c;
    }
    offs[NEXP] = acc;
    *ntiles = nt;
  }
}

__global__ void scatter_kernel(const int* __restrict__ idxbuf, const float* __restrict__ wbuf,
                               const int* __restrict__ offs, int* __restrict__ fill,
                               int* __restrict__ tokb, float* __restrict__ pwb) {
  int gid = blockIdx.x * 256 + threadIdx.x;   // 0..NPAIR-1
  int t = gid >> 3;
  int e = idxbuf[gid];
  int pos = offs[e] + atomicAdd(&fill[e], 1);
  tokb[pos] = t;
  pwb[pos] = wbuf[gid];
}

// ---------------- GEMM (m97-style, fp16 MFMA 16x16x32) ----------------
// A: fp16 [*][K] row-major.  Bmat: fp16 [N][K] row-major (per-expert stride estride).
// MODE 0: silu -> fp16 store (ldo cols). MODE 1: fp32 store. MODE 2: *pw, atomicAdd to tok row.
template <int MODE, bool GATHER_A>
__global__ __launch_bounds__(256)
void gemm_kernel(const f16* __restrict__ A, const f16* __restrict__ Bmat, const int K,
                 const int4* __restrict__ desc, const int* __restrict__ ntiles,
                 const int* __restrict__ tok, const float* __restrict__ pw,
                 void* __restrict__ Out, const int ldo, const long estride) {
  int bx = blockIdx.x, by = blockIdx.y;
  int e = 0, row0, nrows;
  if (desc) {
    if (bx >= *ntiles) return;
    int4 dsc = desc[bx];
    e = dsc.x; row0 = dsc.y; nrows = dsc.z;
  } else {
    row0 = bx * 128; nrows = 128;
  }
  const int n0 = by * 128;
  const f16* Bp = Bmat + (long)e * estride + (long)n0 * K;

  __shared__ f16 As[128 * 32];
  __shared__ f16 Bs[128 * 32];

  const int tid = threadIdx.x;
  // staging: 16B chunk c covers (row=c>>2, kgroup=c&3); thread owns c=tid and c=tid+256
  const int rA0 = tid >> 2, rA1 = (tid + 256) >> 2;
  const int kq0 = (tid & 3) * 8;
  const int lr0 = min(rA0, nrows - 1), lr1 = min(rA1, nrows - 1);
  long tg0, tg1;
  if (GATHER_A) { tg0 = tok[row0 + lr0]; tg1 = tok[row0 + lr1]; }
  else          { tg0 = row0 + lr0;      tg1 = row0 + lr1; }
  const f16* a0 = A + tg0 * K + kq0;
  const f16* a1 = A + tg1 * K + kq0;
  const f16* b0 = Bp + (long)rA0 * K + kq0;
  const f16* b1 = Bp + (long)rA1 * K + kq0;

  f32x4 acc[4][4] = {};
  const int lane = tid & 63, w = tid >> 6;
  const int wro = (w >> 1) * 64, wco = (w & 1) * 64;
  const int fr = lane & 15, kg = (lane >> 4) * 8;

  for (int k0 = 0; k0 < K; k0 += 32) {
    async_ld16(As + tid * 8,        a0 + k0);
    async_ld16(As + tid * 8 + 2048, a1 + k0);
    async_ld16(Bs + tid * 8,        b0 + k0);
    async_ld16(Bs + tid * 8 + 2048, b1 + k0);
    __syncthreads();   // compiler drains vmcnt before s_barrier
    f16x8 af[4], bf[4];
#pragma unroll
    for (int i = 0; i < 4; ++i)
      af[i] = *(const f16x8*)(As + (wro + i * 16 + fr) * 32 + kg);
#pragma unroll
    for (int j = 0; j < 4; ++j)
      bf[j] = *(const f16x8*)(Bs + (wco + j * 16 + fr) * 32 + kg);
#pragma unroll
    for (int i = 0; i < 4; ++i)
#pragma unroll
      for (int j = 0; j < 4; ++j)
        acc[i][j] = __builtin_amdgcn_mfma_f32_16x16x32_f16(af[i], bf[j], acc[i][j], 0, 0, 0);
    __syncthreads();
  }

  // epilogue: D[row=(lane>>4)*4+r, col=lane&15] per 16x16 frag
#pragma unroll
  for (int i = 0; i < 4; ++i) {
    const int mb = wro + i * 16 + (lane >> 4) * 4;
#pragma unroll
    for (int r = 0; r < 4; ++r) {
      const int m = mb + r;
      if (m >= nrows) continue;
      const long gr = row0 + m;
      float wv = 0.f; long orow = 0;
      if (MODE == 2) { wv = pw[gr]; orow = tok[gr]; }
#pragma unroll
      for (int j = 0; j < 4; ++j) {
        const int col = n0 + wco + j * 16 + fr;
        float v = acc[i][j][r];
        if (MODE == 0) {
          float sv = v / (1.f + expf(-v));   // silu
          ((f16*)Out)[gr * ldo + col] = (f16)sv;
        } else if (MODE == 1) {
          ((float*)Out)[gr * ldo + col] = v;
        } else {
          atomicAdd((float*)Out + orow * (long)ldo + col, v * wv);
        }
      }
    }
  }
}

// ---------------- launcher ----------------
extern "C" void kernel_launch(void* const* d_in, const int* in_sizes, int n_in,
                              void* d_out, int out_size, void* d_ws, size_t ws_size,
                              hipStream_t stream) {
  const float* x    = (const float*)d_in[0];
  const float* cent = (const float*)d_in[1];
  const float* bias = (const float*)d_in[2];
  const float* Wsup = (const float*)d_in[3];
  const float* Wsdn = (const float*)d_in[4];
  const float* Wup  = (const float*)d_in[5];
  const float* Wdn  = (const float*)d_in[6];

  char* ws = (char*)d_ws;
  f16*   xh    = (f16*)(ws + OFF_XH);
  f16*   WsupT = (f16*)(ws + OFF_WSUPT);
  f16*   WsdnT = (f16*)(ws + OFF_WSDNT);
  f16*   WupT  = (f16*)(ws + OFF_WUPT);
  f16*   WdnT  = (f16*)(ws + OFF_WDNT);
  f16*   shh   = (f16*)(ws + OFF_SHH);
  f16*   hp    = (f16*)(ws + OFF_HP);
  int*   idx   = (int*)(ws + OFF_IDX);
  float* wb    = (float*)(ws + OFF_WB);
  int*   cnt   = (int*)(ws + OFF_CNT);
  int*   offs  = (int*)(ws + OFF_OFFS);
  int*   fill  = (int*)(ws + OFF_FILL);
  int*   nt    = (int*)(ws + OFF_NT);
  int*   tokb  = (int*)(ws + OFF_TOK);
  float* pwb   = (float*)(ws + OFF_PW);
  int4*  desc  = (int4*)(ws + OFF_DESC);
  float* out   = (float*)d_out;

  zero_cnt_kernel<<<1, 64, 0, stream>>>(cnt);
  routing_kernel<<<T_TOK / 4, 256, 0, stream>>>(x, cent, bias, idx, wb, cnt, xh);
  transpose_f32_f16_kernel<<<dim3(FDIM / 64, DDIM / 64, 1), 256, 0, stream>>>(Wsup, WsupT, DDIM, FDIM);
  transpose_f32_f16_kernel<<<dim3(DDIM / 64, FDIM / 64, 1), 256, 0, stream>>>(Wsdn, WsdnT, FDIM, DDIM);
  transpose_f32_f16_kernel<<<dim3(FDIM / 64, DDIM / 64, NEXP), 256, 0, stream>>>(Wup, WupT, DDIM, FDIM);
  transpose_f32_f16_kernel<<<dim3(DDIM / 64, FDIM / 64, NEXP), 256, 0, stream>>>(Wdn, WdnT, FDIM, DDIM);
  scan_desc_kernel<<<1, 64, 0, stream>>>(cnt, offs, fill, desc, nt);
  scatter_kernel<<<NPAIR / 256, 256, 0, stream>>>(idx, wb, offs, fill, tokb, pwb);

  // shared up: [2048x1024] @ [1024x512] -> silu -> shh
  gemm_kernel<0, false><<<dim3(T_TOK / 128, FDIM / 128), 256, 0, stream>>>(
      xh, WsupT, DDIM, nullptr, nullptr, nullptr, nullptr, shh, FDIM, 0);
  // routed up: gathered rows @ W_up[e] -> silu -> h_pairs
  gemm_kernel<0, true><<<dim3(MAXTILES, FDIM / 128), 256, 0, stream>>>(
      xh, WupT, DDIM, desc, nt, tokb, nullptr, hp, FDIM, (long)FDIM * DDIM);
  // shared down: shh @ [512x1024] -> fp32 store (initializes d_out)
  gemm_kernel<1, false><<<dim3(T_TOK / 128, DDIM / 128), 256, 0, stream>>>(
      shh, WsdnT, FDIM, nullptr, nullptr, nullptr, nullptr, out, DDIM, 0);
  // routed down: h_pairs @ W_down[e] -> *pw -> atomicAdd into d_out token rows
  gemm_kernel<2, false><<<dim3(MAXTILES, DDIM / 128), 256, 0, stream>>>(
      hp, WdnT, FDIM, desc, nt, tokb, pwb, out, DDIM, (long)DDIM * FDIM);
}

// Round 3
// 571.002 us; speedup vs baseline: 1.0860x; 1.0860x over previous
//
#include <hip/hip_runtime.h>
#include <math.h>

typedef _Float16 f16;
typedef _Float16 f16x2 __attribute__((ext_vector_type(2)));
typedef _Float16 f16x4 __attribute__((ext_vector_type(4)));
typedef _Float16 f16x8 __attribute__((ext_vector_type(8)));
typedef float f32x4 __attribute__((ext_vector_type(4)));

#define T_TOK 2048
#define DDIM  1024
#define FDIM  512
#define NEXP  64
#define TOPK  8
#define NPAIR (T_TOK * TOPK)
#define NSHT  (T_TOK / 128)          // 16 shared-expert tiles
#define MAXTILES 192                 // routed: sum ceil(cnt_e/128) <= 128 + 64
#define HPROWS (NPAIR + T_TOK)       // 18432 rows (routed pairs + shared tokens)

// ---------------- workspace layout (bytes) ----------------
static constexpr size_t OFF_XH   = 0;                                        // fp16 [T][D]      4 MiB
static constexpr size_t OFF_AFF  = OFF_XH  + (size_t)T_TOK * DDIM * 2;       // f32  [T][E]      512 KiB
static constexpr size_t OFF_HPA  = OFF_AFF + (size_t)T_TOK * NEXP * 4;       // fp16 [HPROWS][F] 18 MiB
static constexpr size_t OFF_IDX  = OFF_HPA + (size_t)HPROWS * FDIM * 2;      // int  [T][8]
static constexpr size_t OFF_WB   = OFF_IDX + (size_t)NPAIR * 4;              // f32  [T][8]
static constexpr size_t OFF_CNT  = OFF_WB  + (size_t)NPAIR * 4;              // int[64]
static constexpr size_t OFF_OFFS = OFF_CNT + 256;                            // int[65]
static constexpr size_t OFF_FILL = OFF_OFFS + 512;                           // int[64]
static constexpr size_t OFF_NTS  = OFF_FILL + 256;                           // int[2] (up,dn)
static constexpr size_t OFF_TOK  = OFF_NTS + 256;                            // int[HPROWS]
static constexpr size_t OFF_PW   = OFF_TOK + (size_t)HPROWS * 4;             // f32[HPROWS]
static constexpr size_t OFF_DESC = OFF_PW  + (size_t)HPROWS * 4;             // int4[256]

__device__ __forceinline__ void async_ld16(void* lds, const void* g) {
  __builtin_amdgcn_global_load_lds(
      (const __attribute__((address_space(1))) void*)g,
      (__attribute__((address_space(3))) void*)lds, 16, 0, 0);
}

// ---------------- small kernels ----------------
__global__ void zero_cnt_kernel(int* cnt) {
  if (threadIdx.x < NEXP) cnt[threadIdx.x] = 0;
}

// ---------------- aff GEMM (exact fp32) + fused x->fp16 ----------------
// block: 32 tokens x 64 experts; 256 thr; reg tile 2 tok x 4 exp; K-chunks of 128.
__global__ __launch_bounds__(256)
void aff_kernel(const float* __restrict__ x, const float* __restrict__ cent,
                float* __restrict__ aff, f16* __restrict__ xh) {
  __shared__ __align__(16) float xs[32 * 132];   // 528B rows (pad 4)
  __shared__ __align__(16) float cs[64 * 128];   // 512B rows, XOR-swizzled chunks
  const int tid = threadIdx.x;
  const int t0 = blockIdx.x * 32;
  const int tg = tid >> 4;        // 0..15 -> tokens (tg, tg+16)
  const int eg = tid & 15;        // 0..15 -> experts eg*4..+3
  float acc0[4] = {0.f, 0.f, 0.f, 0.f};
  float acc1[4] = {0.f, 0.f, 0.f, 0.f};
  for (int kc = 0; kc < DDIM / 128; ++kc) {
    const int kbase = kc * 128;
    // stage x chunk (1024 float4) + write xh fp16
#pragma unroll
    for (int p = 0; p < 4; ++p) {
      int u = tid + p * 256;
      int row = u >> 5, kk4 = u & 31;
      float4 v = *(const float4*)(x + (size_t)(t0 + row) * DDIM + kbase + kk4 * 4);
      *(float4*)&xs[row * 132 + kk4 * 4] = v;
      f16x4 h = {(f16)v.x, (f16)v.y, (f16)v.z, (f16)v.w};
      *(f16x4*)(xh + (size_t)(t0 + row) * DDIM + kbase + kk4 * 4) = h;
    }
    // stage centroid chunk (2048 float4), XOR-swizzle chunk index by (e>>2)&7
#pragma unroll
    for (int p = 0; p < 8; ++p) {
      int u = tid + p * 256;
      int e = u >> 5, kk4 = u & 31;
      float4 v = *(const float4*)(cent + (size_t)e * DDIM + kbase + kk4 * 4);
      *(float4*)&cs[e * 128 + ((kk4 ^ ((e >> 2) & 7)) << 2)] = v;
    }
    __syncthreads();
#pragma unroll 4
    for (int kk4 = 0; kk4 < 32; ++kk4) {
      float4 xa0 = *(const float4*)&xs[tg * 132 + kk4 * 4];
      float4 xa1 = *(const float4*)&xs[(tg + 16) * 132 + kk4 * 4];
#pragma unroll
      for (int j = 0; j < 4; ++j) {
        int e = eg * 4 + j;
        float4 cb = *(const float4*)&cs[e * 128 + ((kk4 ^ (eg & 7)) << 2)];
        acc0[j] += xa0.x * cb.x + xa0.y * cb.y + xa0.z * cb.z + xa0.w * cb.w;
        acc1[j] += xa1.x * cb.x + xa1.y * cb.y + xa1.z * cb.z + xa1.w * cb.w;
      }
    }
    __syncthreads();
  }
  float4 o0 = {acc0[0], acc0[1], acc0[2], acc0[3]};
  float4 o1 = {acc1[0], acc1[1], acc1[2], acc1[3]};
  *(float4*)(aff + (size_t)(t0 + tg) * NEXP + eg * 4) = o0;
  *(float4*)(aff + (size_t)(t0 + tg + 16) * NEXP + eg * 4) = o1;
}

// ---------------- top-k selection (exact fp32) ----------------
__global__ __launch_bounds__(256)
void topk_kernel(const float* __restrict__ aff, const float* __restrict__ bias,
                 int* __restrict__ idxbuf, float* __restrict__ wbuf,
                 int* __restrict__ cnt) {
  int tid = threadIdx.x;
  int lane = tid & 63, sub = tid >> 6;
  int token = blockIdx.x * 4 + sub;
  float a = aff[(size_t)token * NEXP + lane];
  float sc = a + bias[lane];
  bool picked = false;
  int selidx = 0;
  for (int p = 0; p < TOPK; ++p) {
    float v = picked ? -3.0e38f : sc;
    int ix = lane;
#pragma unroll
    for (int off = 32; off; off >>= 1) {
      float ov = __shfl_xor(v, off);
      int oi = __shfl_xor(ix, off);
      if (ov > v || (ov == v && oi < ix)) { v = ov; ix = oi; }
    }
    if (lane == ix) picked = true;
    if (lane == p) selidx = ix;        // lane p records p-th winner
  }
  float rawa = __shfl(a, selidx);      // unbiased score of selection
  float s = 1.f / (1.f + expf(-rawa));
  float sum = s;
  sum += __shfl_xor(sum, 1); sum += __shfl_xor(sum, 2); sum += __shfl_xor(sum, 4);
  float wg = s / (sum + 1e-8f);
  if (lane < TOPK) {
    idxbuf[token * TOPK + lane] = selidx;
    wbuf[token * TOPK + lane] = wg;
    atomicAdd(&cnt[selidx], 1);
  }
}

// ---------------- scan + tile-descriptor build ----------------
__global__ void scan_desc_kernel(const int* __restrict__ cnt, int* __restrict__ offs,
                                 int* __restrict__ fill, int4* __restrict__ desc,
                                 int* __restrict__ nts) {
  if (threadIdx.x < NEXP) fill[threadIdx.x] = 0;
  if (threadIdx.x == 0) {
    int acc = 0, nt = 0;
    for (int e = 0; e < NEXP; ++e) {
      offs[e] = acc;
      int c = cnt[e];
      for (int r = 0; r < c; r += 128)
        desc[nt++] = make_int4(e, acc + r, min(128, c - r), 0);
      acc += c;
    }
    offs[NEXP] = acc;
    nts[1] = nt;                              // routed-only (down dispatch)
    for (int i = 0; i < NSHT; ++i)            // shared expert pseudo-tiles
      desc[nt++] = make_int4(NEXP, NPAIR + i * 128, 128, 0);
    nts[0] = nt;                              // routed + shared (up dispatch)
  }
}

__global__ void scatter_kernel(const int* __restrict__ idxbuf, const float* __restrict__ wbuf,
                               const int* __restrict__ offs, int* __restrict__ fill,
                               int* __restrict__ tokb, float* __restrict__ pwb) {
  int gid = blockIdx.x * 256 + threadIdx.x;   // 0..HPROWS-1
  if (gid < NPAIR) {
    int t = gid >> 3;
    int e = idxbuf[gid];
    int pos = offs[e] + atomicAdd(&fill[e], 1);
    tokb[pos] = t;
    pwb[pos] = wbuf[gid];
  } else {
    tokb[gid] = gid - NPAIR;                  // identity rows for shared expert
    pwb[gid] = 1.0f;
  }
}

// ---------------- GEMM: A fp16 [rows][K] @ B fp32 [K][N] (cvt->fp16 in-stage) ----------
// MODE 0: silu -> fp16 store. MODE 1: fp32 store. MODE 2: *pw, atomicAdd to tok row.
// desc tile e==NEXP selects B2 (shared weight). B LDS layout: [n][k] 80B rows.
template <int MODE, bool GATHER_A>
__global__ __launch_bounds__(256)
void gemm_kernel(const f16* __restrict__ A, const float* __restrict__ Bmat,
                 const float* __restrict__ B2, const int K, const int ldb,
                 const int4* __restrict__ desc, const int* __restrict__ ntiles,
                 const int* __restrict__ tok, const float* __restrict__ pw,
                 void* __restrict__ Out, const int ldo, const long estride) {
  int bx = blockIdx.x, by = blockIdx.y;
  int e = 0, row0, nrows;
  if (desc) {
    if (bx >= *ntiles) return;
    int4 dsc = desc[bx];
    e = dsc.x; row0 = dsc.y; nrows = dsc.z;
  } else {
    row0 = bx * 128; nrows = 128;
  }
  const int n0 = by * 128;
  const float* Bp = (e == NEXP) ? (B2 + n0) : (Bmat + (long)e * estride + n0);

  __shared__ __align__(16) f16 As[128 * 32];   // [m][k] linear, 64B rows
  __shared__ __align__(16) f16 Bs[128 * 40];   // [n][k-pairs] 80B rows (pad 16B)

  const int tid = threadIdx.x;
  // ---- A staging (global_load_lds, 16B/lane): chunk c = tid, tid+256
  const int rA0 = tid >> 2, rA1 = (tid + 256) >> 2;
  const int kq0 = (tid & 3) * 8;
  const int lr0 = min(rA0, nrows - 1), lr1 = min(rA1, nrows - 1);
  long tg0, tg1;
  if (GATHER_A) { tg0 = tok[row0 + lr0]; tg1 = tok[row0 + lr1]; }
  else          { tg0 = row0 + lr0;      tg1 = row0 + lr1; }
  const f16* a0 = A + tg0 * K + kq0;
  const f16* a1 = A + tg1 * K + kq0;
  // ---- B staging: unit (kp = tid&15, n4 = tid>>4) and (kp, n4+16)
  const int ukp = tid & 15, un4 = tid >> 4;
  const float* bg = Bp + (size_t)(2 * ukp) * ldb + un4 * 4;
  f16x2* bsw = (f16x2*)Bs;                     // word view

  f32x4 acc[4][4] = {};
  const int lane = tid & 63, w = tid >> 6;
  const int wro = (w >> 1) * 64, wco = (w & 1) * 64;
  const int fr = lane & 15, kg = (lane >> 4) * 8;

  for (int k0 = 0; k0 < K; k0 += 32) {
    async_ld16(As + tid * 8,        a0 + k0);
    async_ld16(As + tid * 8 + 2048, a1 + k0);
    const float* bgk = bg + (size_t)k0 * ldb;
    float4 v0 = *(const float4*)bgk;
    float4 v1 = *(const float4*)(bgk + ldb);
    float4 v2 = *(const float4*)(bgk + 64);
    float4 v3 = *(const float4*)(bgk + ldb + 64);
#pragma unroll
    for (int i = 0; i < 4; ++i) {
      float a0i = (i == 0) ? v0.x : (i == 1) ? v0.y : (i == 2) ? v0.z : v0.w;
      float b0i = (i == 0) ? v1.x : (i == 1) ? v1.y : (i == 2) ? v1.z : v1.w;
      float a1i = (i == 0) ? v2.x : (i == 1) ? v2.y : (i == 2) ? v2.z : v2.w;
      float b1i = (i == 0) ? v3.x : (i == 1) ? v3.y : (i == 2) ? v3.z : v3.w;
      bsw[(un4 * 4 + i) * 20 + ukp]        = f16x2{(f16)a0i, (f16)b0i};
      bsw[((un4 + 16) * 4 + i) * 20 + ukp] = f16x2{(f16)a1i, (f16)b1i};
    }
    __syncthreads();   // drains global_load_lds + orders ds_writes
    f16x8 af[4], bf[4];
#pragma unroll
    for (int i = 0; i < 4; ++i)
      af[i] = *(const f16x8*)(As + (wro + i * 16 + fr) * 32 + kg);
#pragma unroll
    for (int j = 0; j < 4; ++j)
      bf[j] = *(const f16x8*)(Bs + (wco + j * 16 + fr) * 40 + kg);
#pragma unroll
    for (int i = 0; i < 4; ++i)
#pragma unroll
      for (int j = 0; j < 4; ++j)
        acc[i][j] = __builtin_amdgcn_mfma_f32_16x16x32_f16(af[i], bf[j], acc[i][j], 0, 0, 0);
    __syncthreads();
  }

  // epilogue: frag D[row=(lane>>4)*4+r, col=lane&15]
#pragma unroll
  for (int i = 0; i < 4; ++i) {
    const int mb = wro + i * 16 + (lane >> 4) * 4;
#pragma unroll
    for (int r = 0; r < 4; ++r) {
      const int m = mb + r;
      if (m >= nrows) continue;
      const long gr = row0 + m;
      float wv = 0.f; long orow = 0;
      if (MODE == 2) { wv = pw[gr]; orow = tok[gr]; }
#pragma unroll
      for (int j = 0; j < 4; ++j) {
        const int col = n0 + wco + j * 16 + fr;
        float v = acc[i][j][r];
        if (MODE == 0) {
          float sv = v / (1.f + expf(-v));   // silu
          ((f16*)Out)[gr * ldo + col] = (f16)sv;
        } else if (MODE == 1) {
          ((float*)Out)[gr * ldo + col] = v;
        } else {
          atomicAdd((float*)Out + orow * (long)ldo + col, v * wv);
        }
      }
    }
  }
}

// ---------------- launcher ----------------
extern "C" void kernel_launch(void* const* d_in, const int* in_sizes, int n_in,
                              void* d_out, int out_size, void* d_ws, size_t ws_size,
                              hipStream_t stream) {
  const float* x    = (const float*)d_in[0];
  const float* cent = (const float*)d_in[1];
  const float* bias = (const float*)d_in[2];
  const float* Wsup = (const float*)d_in[3];   // [D][F] = [K][N] for up
  const float* Wsdn = (const float*)d_in[4];   // [F][D] = [K][N] for down
  const float* Wup  = (const float*)d_in[5];   // [E][D][F]
  const float* Wdn  = (const float*)d_in[6];   // [E][F][D]

  char* ws = (char*)d_ws;
  f16*   xh   = (f16*)(ws + OFF_XH);
  float* aff  = (float*)(ws + OFF_AFF);
  f16*   hpa  = (f16*)(ws + OFF_HPA);
  int*   idx  = (int*)(ws + OFF_IDX);
  float* wb   = (float*)(ws + OFF_WB);
  int*   cnt  = (int*)(ws + OFF_CNT);
  int*   offs = (int*)(ws + OFF_OFFS);
  int*   fill = (int*)(ws + OFF_FILL);
  int*   nts  = (int*)(ws + OFF_NTS);
  int*   tokb = (int*)(ws + OFF_TOK);
  float* pwb  = (float*)(ws + OFF_PW);
  int4*  desc = (int4*)(ws + OFF_DESC);
  float* out  = (float*)d_out;

  zero_cnt_kernel<<<1, 64, 0, stream>>>(cnt);
  aff_kernel<<<T_TOK / 32, 256, 0, stream>>>(x, cent, aff, xh);
  topk_kernel<<<T_TOK / 4, 256, 0, stream>>>(aff, bias, idx, wb, cnt);
  scan_desc_kernel<<<1, 64, 0, stream>>>(cnt, offs, fill, desc, nts);
  scatter_kernel<<<HPROWS / 256, 256, 0, stream>>>(idx, wb, offs, fill, tokb, pwb);

  // up (routed + shared merged): A=xh gathered, B=W_up[e] / Ws_up -> silu -> hpa fp16
  gemm_kernel<0, true><<<dim3(MAXTILES + NSHT, FDIM / 128), 256, 0, stream>>>(
      xh, Wup, Wsup, DDIM, FDIM, desc, &nts[0], tokb, nullptr, hpa, FDIM,
      (long)DDIM * FDIM);
  // shared down: hpa[NPAIR..] @ Ws_down -> fp32 store (initializes d_out)
  gemm_kernel<1, false><<<dim3(T_TOK / 128, DDIM / 128), 256, 0, stream>>>(
      hpa + (size_t)NPAIR * FDIM, Wsdn, nullptr, FDIM, DDIM,
      nullptr, nullptr, nullptr, nullptr, out, DDIM, 0);
  // routed down: hpa pair-rows @ W_down[e] -> *pw -> atomicAdd into d_out token rows
  gemm_kernel<2, false><<<dim3(MAXTILES, DDIM / 128), 256, 0, stream>>>(
      hpa, Wdn, nullptr, FDIM, DDIM, desc, &nts[1], tokb, pwb, out, DDIM,
      (long)FDIM * DDIM);
}

// Round 7
// 520.450 us; speedup vs baseline: 1.1915x; 1.0971x over previous
//
#include <hip/hip_runtime.h>
#include <math.h>

typedef _Float16 f16;
typedef _Float16 f16x2 __attribute__((ext_vector_type(2)));
typedef _Float16 f16x4 __attribute__((ext_vector_type(4)));
typedef _Float16 f16x8 __attribute__((ext_vector_type(8)));
typedef float f32x4 __attribute__((ext_vector_type(4)));

#define T_TOK 2048
#define DDIM  1024
#define FDIM  512
#define NEXP  64
#define TOPK  8
#define NPAIR (T_TOK * TOPK)
#define NSHT  (T_TOK / 128)          // 16 shared-expert tiles
#define MAXTILES 192                 // routed: sum ceil(cnt_e/128) <= 128 + 63
#define HPROWS (NPAIR + T_TOK)       // 18432 rows (routed pairs + shared tokens)

// ---------------- workspace layout (bytes) ----------------
static constexpr size_t OFF_XH   = 0;                                        // fp16 [T][D]      4 MiB
static constexpr size_t OFF_AFF  = OFF_XH  + (size_t)T_TOK * DDIM * 2;       // f32  [T][E]      512 KiB
static constexpr size_t OFF_HPA  = OFF_AFF + (size_t)T_TOK * NEXP * 4;       // fp16 [HPROWS][F] 18 MiB
static constexpr size_t OFF_YP   = OFF_HPA + (size_t)HPROWS * FDIM * 2;      // fp16 [HPROWS][D] 36 MiB
static constexpr size_t OFF_IDX  = OFF_YP  + (size_t)HPROWS * DDIM * 2;      // int  [T][8]
static constexpr size_t OFF_WB   = OFF_IDX + (size_t)NPAIR * 4;              // f32  [T][8]
static constexpr size_t OFF_POS  = OFF_WB  + (size_t)NPAIR * 4;              // int  [T][8]
static constexpr size_t OFF_CNT  = OFF_POS + (size_t)NPAIR * 4;              // int[64]
static constexpr size_t OFF_OFFS = OFF_CNT + 256;                            // int[65]
static constexpr size_t OFF_FILL = OFF_OFFS + 512;                           // int[64]
static constexpr size_t OFF_NTS  = OFF_FILL + 256;                           // int[2]
static constexpr size_t OFF_TOK  = OFF_NTS + 256;                            // int[HPROWS]
static constexpr size_t OFF_DESC = OFF_TOK + (size_t)HPROWS * 4;             // int4[256]

__device__ __forceinline__ void async_ld16(void* lds, const void* g) {
  __builtin_amdgcn_global_load_lds(
      (const __attribute__((address_space(1))) void*)g,
      (__attribute__((address_space(3))) void*)lds, 16, 0, 0);
}

// ---------------- zero (aff + cnt) ----------------
__global__ void zero_kernel(float* __restrict__ aff, int* __restrict__ cnt) {
  int i = blockIdx.x * 256 + threadIdx.x;
  if (i < T_TOK * NEXP / 4) ((float4*)aff)[i] = float4{0.f, 0.f, 0.f, 0.f};
  if (blockIdx.x == 0 && threadIdx.x < NEXP) cnt[threadIdx.x] = 0;
}

// ---------------- aff GEMM (exact fp32, split-K x4) + fused x->fp16 ----------------
// block: 32 tokens x 64 experts, K-slice of 256 (2 chunks of 128); atomic accum.
__global__ __launch_bounds__(256)
void aff_kernel(const float* __restrict__ x, const float* __restrict__ cent,
                float* __restrict__ aff, f16* __restrict__ xh) {
  __shared__ __align__(16) float xs[32 * 132];
  __shared__ __align__(16) float cs[64 * 128];
  const int tid = threadIdx.x;
  const int t0 = blockIdx.x * 32;
  const int kc0 = blockIdx.y * 2;              // 2 chunks of 128 per block
  const int tg = tid >> 4;
  const int eg = tid & 15;
  float acc0[4] = {0.f, 0.f, 0.f, 0.f};
  float acc1[4] = {0.f, 0.f, 0.f, 0.f};
  for (int kc = kc0; kc < kc0 + 2; ++kc) {
    const int kbase = kc * 128;
#pragma unroll
    for (int p = 0; p < 4; ++p) {
      int u = tid + p * 256;
      int row = u >> 5, kk4 = u & 31;
      float4 v = *(const float4*)(x + (size_t)(t0 + row) * DDIM + kbase + kk4 * 4);
      *(float4*)&xs[row * 132 + kk4 * 4] = v;
      f16x4 h = {(f16)v.x, (f16)v.y, (f16)v.z, (f16)v.w};
      *(f16x4*)(xh + (size_t)(t0 + row) * DDIM + kbase + kk4 * 4) = h;
    }
#pragma unroll
    for (int p = 0; p < 8; ++p) {
      int u = tid + p * 256;
      int e = u >> 5, kk4 = u & 31;
      float4 v = *(const float4*)(cent + (size_t)e * DDIM + kbase + kk4 * 4);
      *(float4*)&cs[e * 128 + ((kk4 ^ ((e >> 2) & 7)) << 2)] = v;
    }
    __syncthreads();
#pragma unroll 4
    for (int kk4 = 0; kk4 < 32; ++kk4) {
      float4 xa0 = *(const float4*)&xs[tg * 132 + kk4 * 4];
      float4 xa1 = *(const float4*)&xs[(tg + 16) * 132 + kk4 * 4];
#pragma unroll
      for (int j = 0; j < 4; ++j) {
        int e = eg * 4 + j;
        float4 cb = *(const float4*)&cs[e * 128 + ((kk4 ^ (eg & 7)) << 2)];
        acc0[j] += xa0.x * cb.x + xa0.y * cb.y + xa0.z * cb.z + xa0.w * cb.w;
        acc1[j] += xa1.x * cb.x + xa1.y * cb.y + xa1.z * cb.z + xa1.w * cb.w;
      }
    }
    __syncthreads();
  }
#pragma unroll
  for (int j = 0; j < 4; ++j) {
    atomicAdd(aff + (size_t)(t0 + tg) * NEXP + eg * 4 + j, acc0[j]);
    atomicAdd(aff + (size_t)(t0 + tg + 16) * NEXP + eg * 4 + j, acc1[j]);
  }
}

// ---------------- top-k selection (exact fp32) ----------------
__global__ __launch_bounds__(256)
void topk_kernel(const float* __restrict__ aff, const float* __restrict__ bias,
                 int* __restrict__ idxbuf, float* __restrict__ wbuf,
                 int* __restrict__ cnt) {
  int tid = threadIdx.x;
  int lane = tid & 63, sub = tid >> 6;
  int token = blockIdx.x * 4 + sub;
  float a = aff[(size_t)token * NEXP + lane];
  float sc = a + bias[lane];
  bool picked = false;
  int selidx = 0;
  for (int p = 0; p < TOPK; ++p) {
    float v = picked ? -3.0e38f : sc;
    int ix = lane;
#pragma unroll
    for (int off = 32; off; off >>= 1) {
      float ov = __shfl_xor(v, off);
      int oi = __shfl_xor(ix, off);
      if (ov > v || (ov == v && oi < ix)) { v = ov; ix = oi; }
    }
    if (lane == ix) picked = true;
    if (lane == p) selidx = ix;
  }
  float rawa = __shfl(a, selidx);
  float s = 1.f / (1.f + expf(-rawa));
  float sum = s;
  sum += __shfl_xor(sum, 1); sum += __shfl_xor(sum, 2); sum += __shfl_xor(sum, 4);
  float wg = s / (sum + 1e-8f);
  if (lane < TOPK) {
    idxbuf[token * TOPK + lane] = selidx;
    wbuf[token * TOPK + lane] = wg;
    atomicAdd(&cnt[selidx], 1);
  }
}

// ---------------- scan + tile-descriptor build ----------------
__global__ void scan_desc_kernel(const int* __restrict__ cnt, int* __restrict__ offs,
                                 int* __restrict__ fill, int4* __restrict__ desc,
                                 int* __restrict__ nts) {
  __shared__ int c[NEXP];
  if (threadIdx.x < NEXP) { c[threadIdx.x] = cnt[threadIdx.x]; fill[threadIdx.x] = 0; }
  __syncthreads();
  if (threadIdx.x == 0) {
    int acc = 0, nt = 0;
    for (int e = 0; e < NEXP; ++e) {
      offs[e] = acc;
      int cc = c[e];
      for (int r = 0; r < cc; r += 128)
        desc[nt++] = make_int4(e, acc + r, min(128, cc - r), 0);
      acc += cc;
    }
    offs[NEXP] = acc;
    for (int i = 0; i < NSHT; ++i)
      desc[nt++] = make_int4(NEXP, NPAIR + i * 128, 128, 0);
    nts[0] = nt;
  }
}

__global__ void scatter_kernel(const int* __restrict__ idxbuf, const float* __restrict__ wbuf,
                               const int* __restrict__ offs, int* __restrict__ fill,
                               int* __restrict__ tokb, int* __restrict__ posb) {
  int gid = blockIdx.x * 256 + threadIdx.x;   // 0..HPROWS-1
  if (gid < NPAIR) {
    int t = gid >> 3;
    int e = idxbuf[gid];
    int pos = offs[e] + atomicAdd(&fill[e], 1);
    tokb[pos] = t;
    posb[gid] = pos;                          // token-order -> pair-row map
  } else {
    tokb[gid] = gid - NPAIR;                  // identity rows for shared expert
  }
}

// ---------------- GEMM: A fp16 [rows][K] @ B fp32 [K][N], dbuf-pipelined ----------
// As LDS is chunk-column-major (slot = kq*128 + row, 16B chunks): linear
// global_load_lds dest + permuted per-lane SOURCE; reads index the same map ->
// lanes 0..15 hit 16 consecutive chunks = conflict-free (was 8-way at 64B rows).
// MODE 0: silu -> fp16 store. MODE 1: fp16 store (no act). e==NEXP -> B2 (shared W).
__device__ __forceinline__ void store_b(f16* Bsbuf, int un4, int ukp,
                                        const float4& v0, const float4& v1,
                                        const float4& v2, const float4& v3) {
  f16x2* bsw = (f16x2*)Bsbuf;
#pragma unroll
  for (int i = 0; i < 4; ++i) {
    float a0i = (i == 0) ? v0.x : (i == 1) ? v0.y : (i == 2) ? v0.z : v0.w;
    float b0i = (i == 0) ? v1.x : (i == 1) ? v1.y : (i == 2) ? v1.z : v1.w;
    float a1i = (i == 0) ? v2.x : (i == 1) ? v2.y : (i == 2) ? v2.z : v2.w;
    float b1i = (i == 0) ? v3.x : (i == 1) ? v3.y : (i == 2) ? v3.z : v3.w;
    bsw[(un4 * 4 + i) * 20 + ukp]        = f16x2{(f16)a0i, (f16)b0i};
    bsw[((un4 + 16) * 4 + i) * 20 + ukp] = f16x2{(f16)a1i, (f16)b1i};
  }
}

template <int MODE, bool GATHER_A>
__global__ __launch_bounds__(256)
void gemm_kernel(const f16* __restrict__ A, const float* __restrict__ Bmat,
                 const float* __restrict__ B2, const int K, const int ldb,
                 const int4* __restrict__ desc, const int* __restrict__ ntiles,
                 const int* __restrict__ tok, void* __restrict__ Out,
                 const int ldo, const long estride) {
  const int bx = blockIdx.x, by = blockIdx.y;
  if (bx >= *ntiles) return;
  int4 dsc = desc[bx];
  const int e = dsc.x, row0 = dsc.y, nrows = dsc.z;
  const int n0 = by * 128;
  const float* Bp = (e == NEXP) ? (B2 + n0) : (Bmat + (long)e * estride + n0);

  __shared__ __align__(16) f16 As[2][128 * 32];   // slot-major: [kq][row] 16B chunks
  __shared__ __align__(16) f16 Bs[2][128 * 40];   // [n][k] 80B rows

  const int tid = threadIdx.x;
  // ---- A staging: slots tid (kq = tid>>7) and tid+256 (kq+2), same row tid&127
  const int rS = tid & 127;
  const int kqA = tid >> 7;                    // 0 or 1
  const int lr = min(rS, nrows - 1);
  long tg;
  if (GATHER_A) tg = tok[row0 + lr];
  else          tg = row0 + lr;
  const f16* aA = A + tg * K + kqA * 8;        // slot tid
  const f16* aB = aA + 16;                     // slot tid+256 (kq+2)
  // ---- B staging: (kp = tid&15, n4 = tid>>4) and (kp, n4+16)
  const int ukp = tid & 15, un4 = tid >> 4;
  const float* bg = Bp + (size_t)(2 * ukp) * ldb + un4 * 4;

  f32x4 acc[4][4] = {};
  const int lane = tid & 63, w = tid >> 6;
  const int wro = (w >> 1) * 64, wco = (w & 1) * 64;
  const int fr = lane & 15, kg = (lane >> 4) * 8;
  const int aqo = (lane >> 4) * 1024;          // kq block (128 slots * 8 f16)

  const int NK = K / 32;
  // prologue: stage k-step 0 into buffer 0
  async_ld16(&As[0][tid * 8], aA);
  async_ld16(&As[0][(tid + 256) * 8], aB);
  {
    float4 v0 = *(const float4*)(bg);
    float4 v1 = *(const float4*)(bg + ldb);
    float4 v2 = *(const float4*)(bg + 64);
    float4 v3 = *(const float4*)(bg + ldb + 64);
    store_b(Bs[0], un4, ukp, v0, v1, v2, v3);
  }
  __syncthreads();

  for (int it = 0; it < NK; ++it) {
    const int cur = it & 1, nxt = cur ^ 1;
    const bool more = (it + 1 < NK);
    float4 w0{}, w1{}, w2{}, w3{};
    if (more) {
      const int k0 = (it + 1) * 32;
      async_ld16(&As[nxt][tid * 8], aA + k0);          // next A -> LDS (async)
      async_ld16(&As[nxt][(tid + 256) * 8], aB + k0);
      const float* bgk = bg + (size_t)k0 * ldb;        // next B -> regs (issue early)
      w0 = *(const float4*)(bgk);
      w1 = *(const float4*)(bgk + ldb);
      w2 = *(const float4*)(bgk + 64);
      w3 = *(const float4*)(bgk + ldb + 64);
    }
    f16x8 af[4], bf[4];
#pragma unroll
    for (int i = 0; i < 4; ++i)
      af[i] = *(const f16x8*)(&As[cur][aqo + (wro + i * 16 + fr) * 8]);
#pragma unroll
    for (int j = 0; j < 4; ++j)
      bf[j] = *(const f16x8*)(&Bs[cur][(wco + j * 16 + fr) * 40 + kg]);
#pragma unroll
    for (int i = 0; i < 4; ++i)
#pragma unroll
      for (int j = 0; j < 4; ++j)
        acc[i][j] = __builtin_amdgcn_mfma_f32_16x16x32_f16(af[i], bf[j], acc[i][j], 0, 0, 0);
    if (more)
      store_b(Bs[nxt], un4, ukp, w0, w1, w2, w3);      // write late (latency hidden)
    __syncthreads();
  }

  // epilogue: frag D[row=(lane>>4)*4+r, col=lane&15]
#pragma unroll
  for (int i = 0; i < 4; ++i) {
    const int mb = wro + i * 16 + (lane >> 4) * 4;
#pragma unroll
    for (int r = 0; r < 4; ++r) {
      const int m = mb + r;
      if (m >= nrows) continue;
      const long gr = row0 + m;
#pragma unroll
      for (int j = 0; j < 4; ++j) {
        const int col = n0 + wco + j * 16 + fr;
        float v = acc[i][j][r];
        if (MODE == 0) {
          float sv = v / (1.f + expf(-v));   // silu
          ((f16*)Out)[gr * ldo + col] = (f16)sv;
        } else {
          ((f16*)Out)[gr * ldo + col] = (f16)v;
        }
      }
    }
  }
}

// ---------------- combine: out[t] = y_shared[t] + sum_k w_k * y[pos(t,k)] ----------
__global__ __launch_bounds__(256)
void combine_kernel(const f16* __restrict__ yp, const int* __restrict__ posb,
                    const float* __restrict__ wb, float* __restrict__ out) {
  const int t = blockIdx.x * 2 + (threadIdx.x >> 7);
  const int d8 = (threadIdx.x & 127) * 8;
  f16x8 sv = *(const f16x8*)(yp + (size_t)(NPAIR + t) * DDIM + d8);
  float acc[8];
#pragma unroll
  for (int r = 0; r < 8; ++r) acc[r] = (float)sv[r];
#pragma unroll
  for (int k = 0; k < TOPK; ++k) {
    const int pos = posb[t * TOPK + k];
    const float wk = wb[t * TOPK + k];
    f16x8 v = *(const f16x8*)(yp + (size_t)pos * DDIM + d8);
#pragma unroll
    for (int r = 0; r < 8; ++r) acc[r] += wk * (float)v[r];
  }
  float4 o0 = {acc[0], acc[1], acc[2], acc[3]};
  float4 o1 = {acc[4], acc[5], acc[6], acc[7]};
  *(float4*)(out + (size_t)t * DDIM + d8) = o0;
  *(float4*)(out + (size_t)t * DDIM + d8 + 4) = o1;
}

// ---------------- launcher ----------------
extern "C" void kernel_launch(void* const* d_in, const int* in_sizes, int n_in,
                              void* d_out, int out_size, void* d_ws, size_t ws_size,
                              hipStream_t stream) {
  const float* x    = (const float*)d_in[0];
  const float* cent = (const float*)d_in[1];
  const float* bias = (const float*)d_in[2];
  const float* Wsup = (const float*)d_in[3];   // [D][F] = [K][N] up
  const float* Wsdn = (const float*)d_in[4];   // [F][D] = [K][N] down
  const float* Wup  = (const float*)d_in[5];   // [E][D][F]
  const float* Wdn  = (const float*)d_in[6];   // [E][F][D]

  char* ws = (char*)d_ws;
  f16*   xh   = (f16*)(ws + OFF_XH);
  float* aff  = (float*)(ws + OFF_AFF);
  f16*   hpa  = (f16*)(ws + OFF_HPA);
  f16*   yp   = (f16*)(ws + OFF_YP);
  int*   idx  = (int*)(ws + OFF_IDX);
  float* wb   = (float*)(ws + OFF_WB);
  int*   posb = (int*)(ws + OFF_POS);
  int*   cnt  = (int*)(ws + OFF_CNT);
  int*   offs = (int*)(ws + OFF_OFFS);
  int*   fill = (int*)(ws + OFF_FILL);
  int*   nts  = (int*)(ws + OFF_NTS);
  int*   tokb = (int*)(ws + OFF_TOK);
  int4*  desc = (int4*)(ws + OFF_DESC);
  float* out  = (float*)d_out;

  zero_kernel<<<T_TOK * NEXP / 4 / 256, 256, 0, stream>>>(aff, cnt);
  aff_kernel<<<dim3(T_TOK / 32, 4), 256, 0, stream>>>(x, cent, aff, xh);
  topk_kernel<<<T_TOK / 4, 256, 0, stream>>>(aff, bias, idx, wb, cnt);
  scan_desc_kernel<<<1, 64, 0, stream>>>(cnt, offs, fill, desc, nts);
  scatter_kernel<<<HPROWS / 256, 256, 0, stream>>>(idx, wb, offs, fill, tokb, posb);

  // up (routed + shared): A=xh gathered, B=W_up[e]/Ws_up -> silu -> hpa fp16
  gemm_kernel<0, true><<<dim3(MAXTILES + NSHT, FDIM / 128), 256, 0, stream>>>(
      xh, Wup, Wsup, DDIM, FDIM, desc, nts, tokb, hpa, FDIM, (long)DDIM * FDIM);
  // down (routed + shared): A=hpa rows, B=W_down[e]/Ws_down -> fp16 y_pairs
  gemm_kernel<1, false><<<dim3(MAXTILES + NSHT, DDIM / 128), 256, 0, stream>>>(
      hpa, Wdn, Wsdn, FDIM, DDIM, desc, nts, tokb, yp, DDIM, (long)FDIM * DDIM);
  // combine: weighted sum of pair rows + shared row -> fp32 out
  combine_kernel<<<T_TOK / 2, 256, 0, stream>>>(yp, posb, wb, out);
}